// Round 11
// baseline (740.706 us; speedup 1.0000x reference)
//
#include <hip/hip_runtime.h>
#include <stdint.h>

typedef _Float16 f16_t;
typedef _Float16 f16x8 __attribute__((ext_vector_type(8)));
typedef _Float16 f16x4 __attribute__((ext_vector_type(4)));
typedef float f32x4 __attribute__((ext_vector_type(4)));

#define GLL16(g, l)                                                                   \
  __builtin_amdgcn_global_load_lds((const __attribute__((address_space(1))) uint32_t*)(g), \
                                   (__attribute__((address_space(3))) uint32_t*)(l),  \
                                   16, 0, 0)

// s_waitcnt immediates (gfx9/CDNA encoding: vmcnt[3:0]@0, expcnt@4, lgkmcnt@8, vmcnt[5:4]@14)
#define WAITCNT_VM8 0x0F78   // vmcnt(8), lgkm/exp no-wait
#define WAITCNT_VM0 0x0F70   // vmcnt(0), lgkm/exp no-wait

// ---------------------------------------------------------------------------
// Plain 128x128 GEMM tile mainloop (BK=64, 256 threads, single-buffered).
// ---------------------------------------------------------------------------
__device__ __forceinline__ void gemm_tile(const f16_t* __restrict__ A, long lda,
                                          const f16_t* __restrict__ B, long ldb,
                                          int kTiles, f16_t* lA, f16_t* lB,
                                          f32x4 acc[4][4])
{
  const int tid  = threadIdx.x;
  const int wave = tid >> 6;
  const int lane = tid & 63;

  const f16_t* pA[4];
  const f16_t* pB[4];
  f16_t* lAb[4];
  f16_t* lBb[4];
#pragma unroll
  for (int i = 0; i < 4; ++i) {
    int c  = i * 256 + wave * 64 + lane;
    int m  = c & 127;
    int kq = c >> 7;
    pA[i]  = A + (long)m * lda + kq * 8;
    pB[i]  = B + (long)m * ldb + kq * 8;
    int cb = i * 256 + wave * 64;
    lAb[i] = lA + (long)cb * 8;
    lBb[i] = lB + (long)cb * 8;
  }
  const int lm = lane & 15;
  const int q  = lane >> 4;
  const int wi = (wave >> 1) * 64;
  const int wj = (wave & 1) * 64;

  for (int kt = 0; kt < kTiles; ++kt) {
    long ko = (long)kt * 64;
#pragma unroll
    for (int i = 0; i < 4; ++i) GLL16(pA[i] + ko, lAb[i]);
#pragma unroll
    for (int i = 0; i < 4; ++i) GLL16(pB[i] + ko, lBb[i]);
    __syncthreads();
#pragma unroll
    for (int s = 0; s < 2; ++s) {
      f16x8 af[4], bfr[4];
#pragma unroll
      for (int i = 0; i < 4; ++i)
        af[i] = *(const f16x8*)(lA + (((s * 4 + q) * 128) + wi + i * 16 + lm) * 8);
#pragma unroll
      for (int j = 0; j < 4; ++j)
        bfr[j] = *(const f16x8*)(lB + (((s * 4 + q) * 128) + wj + j * 16 + lm) * 8);
#pragma unroll
      for (int i = 0; i < 4; ++i)
#pragma unroll
        for (int j = 0; j < 4; ++j)
          acc[i][j] = __builtin_amdgcn_mfma_f32_16x16x32_f16(af[i], bfr[j], acc[i][j], 0, 0, 0);
    }
    __syncthreads();
  }
}

// ---------------------------------------------------------------------------
// 128x64 GEMM tile mainloop (BK=64, 256 threads): for occupancy-bound pvf.
// ---------------------------------------------------------------------------
__device__ __forceinline__ void gemm_tile_n64(const f16_t* __restrict__ A, long lda,
                                              const f16_t* __restrict__ B, long ldb,
                                              int kTiles, f16_t* lA, f16_t* lB,
                                              f32x4 acc[4][2])
{
  const int tid  = threadIdx.x;
  const int wave = tid >> 6;
  const int lane = tid & 63;

  const f16_t* pA[4];
  f16_t* lAb[4];
#pragma unroll
  for (int i = 0; i < 4; ++i) {
    int c  = i * 256 + wave * 64 + lane;   // 1024 chunks: kq*128 + m
    int m  = c & 127;
    int kq = c >> 7;
    pA[i]  = A + (long)m * lda + kq * 8;
    lAb[i] = lA + (long)(i * 256 + wave * 64) * 8;
  }
  const f16_t* pB[2];
  f16_t* lBb[2];
#pragma unroll
  for (int i = 0; i < 2; ++i) {
    int c  = i * 256 + wave * 64 + lane;   // 512 chunks: kq*64 + m
    int m  = c & 63;
    int kq = c >> 6;
    pB[i]  = B + (long)m * ldb + kq * 8;
    lBb[i] = lB + (long)(i * 256 + wave * 64) * 8;
  }
  const int lm = lane & 15;
  const int q  = lane >> 4;
  const int wi = (wave >> 1) * 64;
  const int wj = (wave & 1) * 32;

  for (int kt = 0; kt < kTiles; ++kt) {
    long ko = (long)kt * 64;
#pragma unroll
    for (int i = 0; i < 4; ++i) GLL16(pA[i] + ko, lAb[i]);
#pragma unroll
    for (int i = 0; i < 2; ++i) GLL16(pB[i] + ko, lBb[i]);
    __syncthreads();
#pragma unroll
    for (int s = 0; s < 2; ++s) {
      f16x8 af[4], bfr[2];
#pragma unroll
      for (int i = 0; i < 4; ++i)
        af[i] = *(const f16x8*)(lA + (((s * 4 + q) * 128) + wi + i * 16 + lm) * 8);
#pragma unroll
      for (int j = 0; j < 2; ++j)
        bfr[j] = *(const f16x8*)(lB + (((s * 4 + q) * 64) + wj + j * 16 + lm) * 8);
#pragma unroll
      for (int i = 0; i < 4; ++i)
#pragma unroll
        for (int j = 0; j < 2; ++j)
          acc[i][j] = __builtin_amdgcn_mfma_f32_16x16x32_f16(af[i], bfr[j], acc[i][j], 0, 0, 0);
    }
    __syncthreads();
  }
}

// ---------------------------------------------------------------------------
// Fused hi/lo 3-product mainloop, RAW-BARRIER PIPELINED (BK=32, dbuf 64 KB):
// C += Ah*Bh^T + Al*Bh^T + Ah*Bl^T.
// Stage tile k+1, s_waitcnt vmcnt(8) (tile k's loads only), raw s_barrier,
// compute tile k, raw s_barrier. Prefetch never drained (AITER pattern).
// Correctness: vmcnt is per-wave issue-ordered (exactly 8 GLL16/tile);
// MFMA operand deps force ds_read completion before barrier 2; all waves
// pass barrier 2 before anyone stages into the just-read buffer.
// ---------------------------------------------------------------------------
__device__ __forceinline__ void gemm_tile3(const f16_t* __restrict__ Ah,
                                           const f16_t* __restrict__ Al, long lda,
                                           const f16_t* __restrict__ Bh,
                                           const f16_t* __restrict__ Bl, long ldb,
                                           int kTiles, f16_t* lds, f32x4 acc[4][4])
{
  const int tid  = threadIdx.x;
  const int wave = tid >> 6;
  const int lane = tid & 63;

  const f16_t* pAh[2]; const f16_t* pAl[2];
  const f16_t* pBh[2]; const f16_t* pBl[2];
  int dofs[2];
#pragma unroll
  for (int i = 0; i < 2; ++i) {
    int c  = i * 256 + wave * 64 + lane;   // chunk 0..511
    int m  = c & 127;
    int kq = c >> 7;                       // 0..3 (BK=32)
    long aoff = (long)m * lda + kq * 8;
    long boff = (long)m * ldb + kq * 8;
    pAh[i] = Ah + aoff;  pAl[i] = Al + aoff;
    pBh[i] = Bh + boff;  pBl[i] = Bl + boff;
    dofs[i] = (i * 256 + wave * 64) * 8;   // wave-uniform base
  }
  const int lm = lane & 15;
  const int q  = lane >> 4;
  const int wi = (wave >> 1) * 64;
  const int wj = (wave & 1) * 64;

#define STG3(buf, ko)                                                    \
  { f16_t* Lb = lds + (buf) * 16384;                                     \
    _Pragma("unroll") for (int i = 0; i < 2; ++i) {                      \
      GLL16(pAh[i] + (ko), Lb + 0 * 4096 + dofs[i]);                     \
      GLL16(pAl[i] + (ko), Lb + 1 * 4096 + dofs[i]);                     \
      GLL16(pBh[i] + (ko), Lb + 2 * 4096 + dofs[i]);                     \
      GLL16(pBl[i] + (ko), Lb + 3 * 4096 + dofs[i]);                     \
    } }

  STG3(0, 0);
  for (int kt = 0; kt < kTiles; ++kt) {
    int cur = kt & 1;
    if (kt + 1 < kTiles) {
      STG3(1 - cur, (long)(kt + 1) * 32);
      __builtin_amdgcn_s_waitcnt(WAITCNT_VM8);   // wait tile k only
    } else {
      __builtin_amdgcn_s_waitcnt(WAITCNT_VM0);   // last tile: full drain
    }
    __builtin_amdgcn_s_barrier();
    const f16_t* Lb = lds + cur * 16384;
    {
      f16x8 ah[4], al[4], bh[4], bl[4];
#pragma unroll
      for (int i = 0; i < 4; ++i)
        ah[i] = *(const f16x8*)(Lb + 0 * 4096 + (q * 128 + wi + i * 16 + lm) * 8);
#pragma unroll
      for (int j = 0; j < 4; ++j)
        bh[j] = *(const f16x8*)(Lb + 2 * 4096 + (q * 128 + wj + j * 16 + lm) * 8);
#pragma unroll
      for (int i = 0; i < 4; ++i)
#pragma unroll
        for (int j = 0; j < 4; ++j)
          acc[i][j] = __builtin_amdgcn_mfma_f32_16x16x32_f16(ah[i], bh[j], acc[i][j], 0, 0, 0);
#pragma unroll
      for (int i = 0; i < 4; ++i)
        al[i] = *(const f16x8*)(Lb + 1 * 4096 + (q * 128 + wi + i * 16 + lm) * 8);
#pragma unroll
      for (int i = 0; i < 4; ++i)
#pragma unroll
        for (int j = 0; j < 4; ++j)
          acc[i][j] = __builtin_amdgcn_mfma_f32_16x16x32_f16(al[i], bh[j], acc[i][j], 0, 0, 0);
#pragma unroll
      for (int j = 0; j < 4; ++j)
        bl[j] = *(const f16x8*)(Lb + 3 * 4096 + (q * 128 + wj + j * 16 + lm) * 8);
#pragma unroll
      for (int i = 0; i < 4; ++i)
#pragma unroll
        for (int j = 0; j < 4; ++j)
          acc[i][j] = __builtin_amdgcn_mfma_f32_16x16x32_f16(ah[i], bl[j], acc[i][j], 0, 0, 0);
    }
    __builtin_amdgcn_s_barrier();
  }
#undef STG3
}

#define EPI_COORDS                              \
  const int tid  = threadIdx.x;                 \
  const int wave = tid >> 6;                    \
  const int lane = tid & 63;                    \
  const int lm   = lane & 15;                   \
  const int q    = lane >> 4;                   \
  const int wi   = (wave >> 1) * 64;            \
  const int wj   = (wave & 1) * 64;

#define ZERO_ACC(acc)                                            \
  _Pragma("unroll") for (int i = 0; i < 4; ++i)                  \
  _Pragma("unroll") for (int j = 0; j < 4; ++j)                  \
    acc[i][j] = (f32x4){0.f, 0.f, 0.f, 0.f};

// ---- convert fp32 -> f16 hi/lo split, elementwise (vector x4)
__global__ __launch_bounds__(256) void k_cvt_split(const float* __restrict__ src,
                                                   f16_t* __restrict__ hi,
                                                   f16_t* __restrict__ lo)
{
  long i = ((long)blockIdx.x * 256 + threadIdx.x) * 4;
  float4 v = *(const float4*)(src + i);
  f16_t h0 = (f16_t)v.x, h1 = (f16_t)v.y, h2 = (f16_t)v.z, h3 = (f16_t)v.w;
  f16x4 hv = {h0, h1, h2, h3};
  f16x4 lv = {(f16_t)(v.x - (float)h0), (f16_t)(v.y - (float)h1),
              (f16_t)(v.z - (float)h2), (f16_t)(v.w - (float)h3)};
  *(f16x4*)(hi + i) = hv;
  *(f16x4*)(lo + i) = lv;
}

// ---- merged transposes: z<3 -> W branch z (768x768, hi+lo); z==3 -> params
__global__ __launch_bounds__(256) void k_transpose_all(const float* __restrict__ w0,
                                                       const float* __restrict__ w1,
                                                       const float* __restrict__ w2,
                                                       const float* __restrict__ params,
                                                       f16_t* __restrict__ Wh,
                                                       f16_t* __restrict__ Wl,
                                                       f16_t* __restrict__ paramsT)
{
  __shared__ float t[32][33];
  const int z = blockIdx.z;
  const float* src;
  f16_t* hi;
  f16_t* lo;
  int R, C;
  if (z < 3) {
    if (blockIdx.y >= 24) return;
    src = (z == 0) ? w0 : ((z == 1) ? w1 : w2);
    hi  = Wh + (long)z * 768 * 768;
    lo  = Wl + (long)z * 768 * 768;
    R = 768; C = 768;
  } else {
    src = params; hi = paramsT; lo = nullptr;
    R = 2304; C = 768;
  }
  int x = blockIdx.x * 32 + threadIdx.x;
  int y = blockIdx.y * 32 + threadIdx.y;
#pragma unroll
  for (int j = 0; j < 32; j += 8)
    t[threadIdx.y + j][threadIdx.x] = src[(long)(y + j) * C + x];
  __syncthreads();
  int x2 = blockIdx.y * 32 + threadIdx.x;
  int y2 = blockIdx.x * 32 + threadIdx.y;
#pragma unroll
  for (int j = 0; j < 32; j += 8) {
    float v  = t[threadIdx.x][threadIdx.y + j];
    long idx = (long)(y2 + j) * R + x2;
    f16_t h  = (f16_t)v;
    hi[idx] = h;
    if (lo) lo[idx] = (f16_t)(v - (float)h);
  }
}

// ---- merged tw + vt dispatch. z < g: tw slot z (pipelined fused 3-pass).
//      z >= g: vt block (Vt[br][b] = (node_b @ P_br)^T), linear id decode.
__global__ __launch_bounds__(256, 4) void k_tw_vt(const f16_t* __restrict__ nh,
                                                  const f16_t* __restrict__ nl,
                                                  const f16_t* __restrict__ Wh,
                                                  const f16_t* __restrict__ Wl,
                                                  const f16_t* __restrict__ paramsT,
                                                  f16_t* __restrict__ Thi,
                                                  f16_t* __restrict__ Tlo,
                                                  f16_t* __restrict__ Vt,
                                                  int br_base, int g)
{
  __shared__ __align__(16) f16_t lds[2 * 16384];   // 64 KB
  if ((int)blockIdx.z < g) {
    f32x4 acc[4][4];
    ZERO_ACC(acc);
    const int slot = blockIdx.z;
    const long br  = br_base + slot;
    long aofs = (long)blockIdx.x * 128 * 768;
    long bofs = br * 768 * 768 + (long)blockIdx.y * 128 * 768;
    gemm_tile3(nh + aofs, nl + aofs, 768, Wh + bofs, Wl + bofs, 768, 24, lds, acc);
    EPI_COORDS;
    long out0 = (long)slot * 8192 * 768;
    long row0 = (long)blockIdx.x * 128;
    long col0 = (long)blockIdx.y * 128;
#pragma unroll
    for (int i = 0; i < 4; ++i)
#pragma unroll
      for (int j = 0; j < 4; ++j)
#pragma unroll
        for (int r = 0; r < 4; ++r) {
          long row = row0 + wi + i * 16 + q * 4 + r;
          long col = col0 + wj + j * 16 + lm;
          float v  = acc[i][j][r];
          f16_t h  = (f16_t)v;
          Thi[out0 + row * 768 + col] = h;
          Tlo[out0 + row * 768 + col] = (f16_t)(v - (float)h);
        }
  } else {
    int id   = blockIdx.x + 64 * (blockIdx.y + 6 * (blockIdx.z - g));  // 0..1151
    int vx   = id % 6;
    int rest = id / 6;
    int vy   = rest & 7;
    int vz   = rest >> 3;        // 0..23
    int b    = vz & 7;
    int br   = vz >> 3;
    f32x4 acc[4][4];
    ZERO_ACC(acc);
    const f16_t* A = paramsT + (long)vx * 128 * 2304 + (long)br * 768;
    const f16_t* B = nh + ((long)b * 1024 + (long)vy * 128) * 768;
    gemm_tile(A, 2304, B, 768, 12, lds, lds + 8192, acc);
    EPI_COORDS;
    f16_t* C = Vt + ((long)(br * 8 + b) * 768) * 1024;
    long row0 = (long)vx * 128;
    long col0 = (long)vy * 128;
#pragma unroll
    for (int i = 0; i < 4; ++i)
#pragma unroll
      for (int j = 0; j < 4; ++j)
#pragma unroll
        for (int r = 0; r < 4; ++r) {
          long row = row0 + wi + i * 16 + q * 4 + r;
          long col = col0 + wj + j * 16 + lm;
          C[row * 1024 + col] = (f16_t)acc[i][j][r];
        }
  }
}

// ---- GEMM2 (pipelined fused-3): S = T @ node^T, masked, fp32
//      grid (8, 8, 8g); XCD-supertile swizzled
__global__ __launch_bounds__(256, 4) void k_gemm_scores(const f16_t* __restrict__ Thi,
                                                        const f16_t* __restrict__ Tlo,
                                                        const f16_t* __restrict__ nh,
                                                        const f16_t* __restrict__ nl,
                                                        const int* __restrict__ adj0,
                                                        const int* __restrict__ adj1,
                                                        const int* __restrict__ adj2,
                                                        float* __restrict__ S, int br_base)
{
  __shared__ __align__(16) f16_t lds[2 * 16384];   // 64 KB
  f32x4 acc[4][4];
  ZERO_ACC(acc);
  const int g    = gridDim.z >> 3;
  int id   = blockIdx.x + (blockIdx.y << 3) + (blockIdx.z << 6);
  int xcd  = id & 7;
  int step = id >> 3;
  int zz   = xcd * g + (step >> 6);
  int s    = step & 63;
  int bx   = s & 7;
  int by   = s >> 3;
  const int b    = zz & 7;
  const int slot = zz >> 3;
  const int br   = br_base + slot;
  const int* adj = (br == 0) ? adj0 : ((br == 1) ? adj1 : adj2);
  long arow = (long)slot * 8192 * 768 + ((long)b * 1024 + (long)bx * 128) * 768;
  long brow = ((long)b * 1024 + (long)by * 128) * 768;
  gemm_tile3(Thi + arow, Tlo + arow, 768, nh + brow, nl + brow, 768, 24, lds, acc);
  EPI_COORDS;
  const int* adjb = adj + (long)b * 1024 * 1024;
  float* Sb = S + ((long)slot * 8 + b) * 1024 * 1024;
  long row0 = (long)bx * 128;
  long col0 = (long)by * 128;
#pragma unroll
  for (int i = 0; i < 4; ++i)
#pragma unroll
    for (int j = 0; j < 4; ++j)
#pragma unroll
      for (int r = 0; r < 4; ++r) {
        long row = row0 + wi + i * 16 + q * 4 + r;
        long col = col0 + wj + j * 16 + lm;
        float v  = acc[i][j][r];
        v = (adjb[row * 1024 + col] == 1) ? v : -1e7f;
        Sb[row * 1024 + col] = v;
      }
}

// ---- row softmax: fp32 S row -> f16 att written IN-PLACE (row stride 2048 f16)
__global__ __launch_bounds__(256) void k_softmax(float* __restrict__ S)
{
  long row = blockIdx.x;
  float* rowp = S + row * 1024;
  float4 v = ((const float4*)rowp)[threadIdx.x];
  float m = fmaxf(fmaxf(v.x, v.y), fmaxf(v.z, v.w));
#pragma unroll
  for (int off = 32; off; off >>= 1) m = fmaxf(m, __shfl_xor(m, off));
  __shared__ float redm[4];
  __shared__ float reds[4];
  int wave = threadIdx.x >> 6, lane = threadIdx.x & 63;
  if (lane == 0) redm[wave] = m;
  __syncthreads();   // also: all row reads complete before any in-place write
  m = fmaxf(fmaxf(redm[0], redm[1]), fmaxf(redm[2], redm[3]));
  float e0 = __expf(v.x - m), e1 = __expf(v.y - m), e2 = __expf(v.z - m), e3 = __expf(v.w - m);
  float s = e0 + e1 + e2 + e3;
#pragma unroll
  for (int off = 32; off; off >>= 1) s += __shfl_xor(s, off);
  if (lane == 0) reds[wave] = s;
  __syncthreads();
  s = reds[0] + reds[1] + reds[2] + reds[3];
  float inv = 1.0f / s;
  f16x4 o = {(f16_t)(e0 * inv), (f16_t)(e1 * inv), (f16_t)(e2 * inv), (f16_t)(e3 * inv)};
  *(f16x4*)((f16_t*)rowp + threadIdx.x * 4) = o;
}

// ---- GEMM-PVF (fused pv+final, 128x64 tiles for occupancy):
//      out (+)= sum_slot att_slot @ V[br_base+slot]; grid (8, 12, 8)
__global__ __launch_bounds__(256, 4) void k_gemm_pvf(const float* __restrict__ S,
                                                     const f16_t* __restrict__ Vt,
                                                     float* __restrict__ out,
                                                     int g, int br_base)
{
  __shared__ __align__(16) f16_t lA[128 * 64];  // 16 KB
  __shared__ __align__(16) f16_t lB[64 * 64];   // 8 KB
  f32x4 acc[4][2];
#pragma unroll
  for (int i = 0; i < 4; ++i)
#pragma unroll
    for (int j = 0; j < 2; ++j)
      acc[i][j] = (f32x4){0.f, 0.f, 0.f, 0.f};
  const int b = blockIdx.z;
  for (int s = 0; s < g; ++s) {
    const f16_t* att = (const f16_t*)(S + (long)s * 8 * 1024 * 1024);
    const f16_t* A = att + ((long)b * 1024 + (long)blockIdx.x * 128) * 2048;
    const f16_t* B = Vt + (((long)(br_base + s) * 8 + b) * 768 + (long)blockIdx.y * 64) * 1024;
    gemm_tile_n64(A, 2048, B, 1024, 16, lA, lB, acc);
  }
  const int tid  = threadIdx.x;
  const int wave = tid >> 6;
  const int lane = tid & 63;
  const int lm   = lane & 15;
  const int q    = lane >> 4;
  const int wi   = (wave >> 1) * 64;
  const int wj   = (wave & 1) * 32;
  float* Cb = out + (long)b * 1024 * 768;
  long row0 = (long)blockIdx.x * 128;
  long col0 = (long)blockIdx.y * 64;
#pragma unroll
  for (int i = 0; i < 4; ++i)
#pragma unroll
    for (int j = 0; j < 2; ++j)
#pragma unroll
      for (int r = 0; r < 4; ++r) {
        long row = row0 + wi + i * 16 + q * 4 + r;
        long col = col0 + wj + j * 16 + lm;
        float v  = acc[i][j][r];
        if (br_base != 0) v += Cb[row * 768 + col];
        Cb[row * 768 + col] = v;
      }
}

extern "C" void kernel_launch(void* const* d_in, const int* in_sizes, int n_in,
                              void* d_out, int out_size, void* d_ws, size_t ws_size,
                              hipStream_t stream)
{
  const float* node    = (const float*)d_in[0];
  const int*   adjp[3] = {(const int*)d_in[1], (const int*)d_in[2], (const int*)d_in[3]};
  const float* Wp[3]   = {(const float*)d_in[4], (const float*)d_in[5], (const float*)d_in[6]};
  const float* params  = (const float*)d_in[7];
  float* out = (float*)d_out;

  const size_t SZ_W3 = 3ull * 768 * 768 * 2;     // f16 [3][768][768]
  const size_t SZ_PT = 768ull * 2304 * 2;        // f16 [768][2304]
  const size_t SZ_N  = 8192ull * 768 * 2;        // f16 [8192][768]
  const size_t SZ_VT = 24ull * 768 * 1024 * 2;   // f16 [3][8][768][1024]
  const size_t SZ_T  = 8192ull * 768 * 2;        // f16 per slot (Thi / Tlo)
  const size_t SZ_S  = 8ull * 1024 * 1024 * 4;   // fp32 per slot (S, later att overlay)
  const size_t FIXED = 2 * SZ_W3 + SZ_PT + 2 * SZ_N + SZ_VT;
  const size_t SLOT  = 2 * SZ_T + SZ_S;

  int NBR = 1;
  if (ws_size >= FIXED + 3 * SLOT) NBR = 3;
  else if (ws_size >= FIXED + 2 * SLOT) NBR = 2;
  else if (ws_size < FIXED + SLOT) return;  // can't run

  char* base = (char*)d_ws;
  size_t off = 0;
  f16_t* Wh      = (f16_t*)(base + off); off += SZ_W3;
  f16_t* Wl      = (f16_t*)(base + off); off += SZ_W3;
  f16_t* paramsT = (f16_t*)(base + off); off += SZ_PT;
  f16_t* node_hi = (f16_t*)(base + off); off += SZ_N;
  f16_t* node_lo = (f16_t*)(base + off); off += SZ_N;
  f16_t* Vt      = (f16_t*)(base + off); off += SZ_VT;
  f16_t* Thi     = (f16_t*)(base + off); off += (size_t)NBR * SZ_T;
  f16_t* Tlo     = (f16_t*)(base + off); off += (size_t)NBR * SZ_T;
  float* S       = (float*)(base + off); off += (size_t)NBR * SZ_S;

  k_cvt_split<<<6144, 256, 0, stream>>>(node, node_hi, node_lo);
  k_transpose_all<<<dim3(24, 72, 4), dim3(32, 8), 0, stream>>>(Wp[0], Wp[1], Wp[2], params,
                                                               Wh, Wl, paramsT);

  int done = 0;
  while (done < 3) {
    int g = (3 - done < NBR) ? (3 - done) : NBR;
    int vtz = (done == 0) ? 3 : 0;
    k_tw_vt<<<dim3(64, 6, g + vtz), 256, 0, stream>>>(node_hi, node_lo, Wh, Wl, paramsT,
                                                      Thi, Tlo, Vt, done, g);
    k_gemm_scores<<<dim3(8, 8, 8 * g), 256, 0, stream>>>(Thi, Tlo, node_hi, node_lo,
                                                         adjp[0], adjp[1], adjp[2], S, done);
    k_softmax<<<8192 * g, 256, 0, stream>>>(S);
    k_gemm_pvf<<<dim3(8, 12, 8), 256, 0, stream>>>(S, Vt, out, g, done);
    done += g;
  }
}

// Round 12
// 684.500 us; speedup vs baseline: 1.0821x; 1.0821x over previous
//
#include <hip/hip_runtime.h>
#include <stdint.h>

typedef _Float16 f16_t;
typedef _Float16 f16x8 __attribute__((ext_vector_type(8)));
typedef _Float16 f16x4 __attribute__((ext_vector_type(4)));
typedef float f32x4 __attribute__((ext_vector_type(4)));

#define GLL16(g, l)                                                                   \
  __builtin_amdgcn_global_load_lds((const __attribute__((address_space(1))) uint32_t*)(g), \
                                   (__attribute__((address_space(3))) uint32_t*)(l),  \
                                   16, 0, 0)

// ---------------------------------------------------------------------------
// Plain 128x128 GEMM tile mainloop (BK=64, 256 threads, single-buffered).
// Proven plateau core (rounds 6/8/10); r7 dbuf, r9 256-tile, r11 raw-barrier
// all regressed — do not touch.
// ---------------------------------------------------------------------------
__device__ __forceinline__ void gemm_tile(const f16_t* __restrict__ A, long lda,
                                          const f16_t* __restrict__ B, long ldb,
                                          int kTiles, f16_t* lA, f16_t* lB,
                                          f32x4 acc[4][4])
{
  const int tid  = threadIdx.x;
  const int wave = tid >> 6;
  const int lane = tid & 63;

  const f16_t* pA[4];
  const f16_t* pB[4];
  f16_t* lAb[4];
  f16_t* lBb[4];
#pragma unroll
  for (int i = 0; i < 4; ++i) {
    int c  = i * 256 + wave * 64 + lane;
    int m  = c & 127;
    int kq = c >> 7;
    pA[i]  = A + (long)m * lda + kq * 8;
    pB[i]  = B + (long)m * ldb + kq * 8;
    int cb = i * 256 + wave * 64;
    lAb[i] = lA + (long)cb * 8;
    lBb[i] = lB + (long)cb * 8;
  }
  const int lm = lane & 15;
  const int q  = lane >> 4;
  const int wi = (wave >> 1) * 64;
  const int wj = (wave & 1) * 64;

  for (int kt = 0; kt < kTiles; ++kt) {
    long ko = (long)kt * 64;
#pragma unroll
    for (int i = 0; i < 4; ++i) GLL16(pA[i] + ko, lAb[i]);
#pragma unroll
    for (int i = 0; i < 4; ++i) GLL16(pB[i] + ko, lBb[i]);
    __syncthreads();
#pragma unroll
    for (int s = 0; s < 2; ++s) {
      f16x8 af[4], bfr[4];
#pragma unroll
      for (int i = 0; i < 4; ++i)
        af[i] = *(const f16x8*)(lA + (((s * 4 + q) * 128) + wi + i * 16 + lm) * 8);
#pragma unroll
      for (int j = 0; j < 4; ++j)
        bfr[j] = *(const f16x8*)(lB + (((s * 4 + q) * 128) + wj + j * 16 + lm) * 8);
#pragma unroll
      for (int i = 0; i < 4; ++i)
#pragma unroll
        for (int j = 0; j < 4; ++j)
          acc[i][j] = __builtin_amdgcn_mfma_f32_16x16x32_f16(af[i], bfr[j], acc[i][j], 0, 0, 0);
    }
    __syncthreads();
  }
}

// ---------------------------------------------------------------------------
// 128x64 GEMM tile mainloop (BK=64, 256 threads): for occupancy-bound pvf.
// ---------------------------------------------------------------------------
__device__ __forceinline__ void gemm_tile_n64(const f16_t* __restrict__ A, long lda,
                                              const f16_t* __restrict__ B, long ldb,
                                              int kTiles, f16_t* lA, f16_t* lB,
                                              f32x4 acc[4][2])
{
  const int tid  = threadIdx.x;
  const int wave = tid >> 6;
  const int lane = tid & 63;

  const f16_t* pA[4];
  f16_t* lAb[4];
#pragma unroll
  for (int i = 0; i < 4; ++i) {
    int c  = i * 256 + wave * 64 + lane;   // 1024 chunks: kq*128 + m
    int m  = c & 127;
    int kq = c >> 7;
    pA[i]  = A + (long)m * lda + kq * 8;
    lAb[i] = lA + (long)(i * 256 + wave * 64) * 8;
  }
  const f16_t* pB[2];
  f16_t* lBb[2];
#pragma unroll
  for (int i = 0; i < 2; ++i) {
    int c  = i * 256 + wave * 64 + lane;   // 512 chunks: kq*64 + m
    int m  = c & 63;
    int kq = c >> 6;
    pB[i]  = B + (long)m * ldb + kq * 8;
    lBb[i] = lB + (long)(i * 256 + wave * 64) * 8;
  }
  const int lm = lane & 15;
  const int q  = lane >> 4;
  const int wi = (wave >> 1) * 64;
  const int wj = (wave & 1) * 32;

  for (int kt = 0; kt < kTiles; ++kt) {
    long ko = (long)kt * 64;
#pragma unroll
    for (int i = 0; i < 4; ++i) GLL16(pA[i] + ko, lAb[i]);
#pragma unroll
    for (int i = 0; i < 2; ++i) GLL16(pB[i] + ko, lBb[i]);
    __syncthreads();
#pragma unroll
    for (int s = 0; s < 2; ++s) {
      f16x8 af[4], bfr[2];
#pragma unroll
      for (int i = 0; i < 4; ++i)
        af[i] = *(const f16x8*)(lA + (((s * 4 + q) * 128) + wi + i * 16 + lm) * 8);
#pragma unroll
      for (int j = 0; j < 2; ++j)
        bfr[j] = *(const f16x8*)(lB + (((s * 4 + q) * 64) + wj + j * 16 + lm) * 8);
#pragma unroll
      for (int i = 0; i < 4; ++i)
#pragma unroll
        for (int j = 0; j < 2; ++j)
          acc[i][j] = __builtin_amdgcn_mfma_f32_16x16x32_f16(af[i], bfr[j], acc[i][j], 0, 0, 0);
    }
    __syncthreads();
  }
}

// ---------------------------------------------------------------------------
// Fused hi/lo 3-product mainloop (BK=32, single-buffered, proven):
// C += Ah*Bh^T + Al*Bh^T + Ah*Bl^T. 4 LDS bufs x 8 KB = 32 KB.
// ---------------------------------------------------------------------------
__device__ __forceinline__ void gemm_tile3(const f16_t* __restrict__ Ah,
                                           const f16_t* __restrict__ Al, long lda,
                                           const f16_t* __restrict__ Bh,
                                           const f16_t* __restrict__ Bl, long ldb,
                                           int kTiles,
                                           f16_t* lAh, f16_t* lAl,
                                           f16_t* lBh, f16_t* lBl,
                                           f32x4 acc[4][4])
{
  const int tid  = threadIdx.x;
  const int wave = tid >> 6;
  const int lane = tid & 63;

  const f16_t* pAh[2]; const f16_t* pAl[2];
  const f16_t* pBh[2]; const f16_t* pBl[2];
  f16_t* dAh[2]; f16_t* dAl[2]; f16_t* dBh[2]; f16_t* dBl[2];
#pragma unroll
  for (int i = 0; i < 2; ++i) {
    int c  = i * 256 + wave * 64 + lane;   // chunk 0..511
    int m  = c & 127;
    int kq = c >> 7;                       // 0..3 (BK=32)
    long aoff = (long)m * lda + kq * 8;
    long boff = (long)m * ldb + kq * 8;
    pAh[i] = Ah + aoff;  pAl[i] = Al + aoff;
    pBh[i] = Bh + boff;  pBl[i] = Bl + boff;
    int cb = i * 256 + wave * 64;
    dAh[i] = lAh + (long)cb * 8;  dAl[i] = lAl + (long)cb * 8;
    dBh[i] = lBh + (long)cb * 8;  dBl[i] = lBl + (long)cb * 8;
  }
  const int lm = lane & 15;
  const int q  = lane >> 4;
  const int wi = (wave >> 1) * 64;
  const int wj = (wave & 1) * 64;

  for (int kt = 0; kt < kTiles; ++kt) {
    long ko = (long)kt * 32;
#pragma unroll
    for (int i = 0; i < 2; ++i) GLL16(pAh[i] + ko, dAh[i]);
#pragma unroll
    for (int i = 0; i < 2; ++i) GLL16(pAl[i] + ko, dAl[i]);
#pragma unroll
    for (int i = 0; i < 2; ++i) GLL16(pBh[i] + ko, dBh[i]);
#pragma unroll
    for (int i = 0; i < 2; ++i) GLL16(pBl[i] + ko, dBl[i]);
    __syncthreads();
    {
      f16x8 ah[4], al[4], bh[4], bl[4];
#pragma unroll
      for (int i = 0; i < 4; ++i)
        ah[i] = *(const f16x8*)(lAh + (q * 128 + wi + i * 16 + lm) * 8);
#pragma unroll
      for (int j = 0; j < 4; ++j)
        bh[j] = *(const f16x8*)(lBh + (q * 128 + wj + j * 16 + lm) * 8);
#pragma unroll
      for (int i = 0; i < 4; ++i)
#pragma unroll
        for (int j = 0; j < 4; ++j)
          acc[i][j] = __builtin_amdgcn_mfma_f32_16x16x32_f16(ah[i], bh[j], acc[i][j], 0, 0, 0);
#pragma unroll
      for (int i = 0; i < 4; ++i)
        al[i] = *(const f16x8*)(lAl + (q * 128 + wi + i * 16 + lm) * 8);
#pragma unroll
      for (int i = 0; i < 4; ++i)
#pragma unroll
        for (int j = 0; j < 4; ++j)
          acc[i][j] = __builtin_amdgcn_mfma_f32_16x16x32_f16(al[i], bh[j], acc[i][j], 0, 0, 0);
#pragma unroll
      for (int j = 0; j < 4; ++j)
        bl[j] = *(const f16x8*)(lBl + (q * 128 + wj + j * 16 + lm) * 8);
#pragma unroll
      for (int i = 0; i < 4; ++i)
#pragma unroll
        for (int j = 0; j < 4; ++j)
          acc[i][j] = __builtin_amdgcn_mfma_f32_16x16x32_f16(ah[i], bl[j], acc[i][j], 0, 0, 0);
    }
    __syncthreads();
  }
}

#define EPI_COORDS                              \
  const int tid  = threadIdx.x;                 \
  const int wave = tid >> 6;                    \
  const int lane = tid & 63;                    \
  const int lm   = lane & 15;                   \
  const int q    = lane >> 4;                   \
  const int wi   = (wave >> 1) * 64;            \
  const int wj   = (wave & 1) * 64;

#define ZERO_ACC(acc)                                            \
  _Pragma("unroll") for (int i = 0; i < 4; ++i)                  \
  _Pragma("unroll") for (int j = 0; j < 4; ++j)                  \
    acc[i][j] = (f32x4){0.f, 0.f, 0.f, 0.f};

// ---- convert fp32 -> f16 hi/lo split, elementwise (vector x4)
__global__ __launch_bounds__(256) void k_cvt_split(const float* __restrict__ src,
                                                   f16_t* __restrict__ hi,
                                                   f16_t* __restrict__ lo)
{
  long i = ((long)blockIdx.x * 256 + threadIdx.x) * 4;
  float4 v = *(const float4*)(src + i);
  f16_t h0 = (f16_t)v.x, h1 = (f16_t)v.y, h2 = (f16_t)v.z, h3 = (f16_t)v.w;
  f16x4 hv = {h0, h1, h2, h3};
  f16x4 lv = {(f16_t)(v.x - (float)h0), (f16_t)(v.y - (float)h1),
              (f16_t)(v.z - (float)h2), (f16_t)(v.w - (float)h3)};
  *(f16x4*)(hi + i) = hv;
  *(f16x4*)(lo + i) = lv;
}

// ---- merged transposes: z<3 -> W branch z (768x768, hi+lo); z==3 -> params
__global__ __launch_bounds__(256) void k_transpose_all(const float* __restrict__ w0,
                                                       const float* __restrict__ w1,
                                                       const float* __restrict__ w2,
                                                       const float* __restrict__ params,
                                                       f16_t* __restrict__ Wh,
                                                       f16_t* __restrict__ Wl,
                                                       f16_t* __restrict__ paramsT)
{
  __shared__ float t[32][33];
  const int z = blockIdx.z;
  const float* src;
  f16_t* hi;
  f16_t* lo;
  int R, C;
  if (z < 3) {
    if (blockIdx.y >= 24) return;
    src = (z == 0) ? w0 : ((z == 1) ? w1 : w2);
    hi  = Wh + (long)z * 768 * 768;
    lo  = Wl + (long)z * 768 * 768;
    R = 768; C = 768;
  } else {
    src = params; hi = paramsT; lo = nullptr;
    R = 2304; C = 768;
  }
  int x = blockIdx.x * 32 + threadIdx.x;
  int y = blockIdx.y * 32 + threadIdx.y;
#pragma unroll
  for (int j = 0; j < 32; j += 8)
    t[threadIdx.y + j][threadIdx.x] = src[(long)(y + j) * C + x];
  __syncthreads();
  int x2 = blockIdx.y * 32 + threadIdx.x;
  int y2 = blockIdx.x * 32 + threadIdx.y;
#pragma unroll
  for (int j = 0; j < 32; j += 8) {
    float v  = t[threadIdx.x][threadIdx.y + j];
    long idx = (long)(y2 + j) * R + x2;
    f16_t h  = (f16_t)v;
    hi[idx] = h;
    if (lo) lo[idx] = (f16_t)(v - (float)h);
  }
}

// ---- merged tw + vt dispatch. z < g: tw slot z (fused 3-pass node@W).
//      z >= g: vt block (Vt[br][b] = (node_b @ P_br)^T), linear id decode.
__global__ __launch_bounds__(256, 4) void k_tw_vt(const f16_t* __restrict__ nh,
                                                  const f16_t* __restrict__ nl,
                                                  const f16_t* __restrict__ Wh,
                                                  const f16_t* __restrict__ Wl,
                                                  const f16_t* __restrict__ paramsT,
                                                  f16_t* __restrict__ Thi,
                                                  f16_t* __restrict__ Tlo,
                                                  f16_t* __restrict__ Vt,
                                                  int br_base, int g)
{
  __shared__ __align__(16) f16_t lds[16384];   // 32 KB, shared by both roles
  if ((int)blockIdx.z < g) {
    f32x4 acc[4][4];
    ZERO_ACC(acc);
    const int slot = blockIdx.z;
    const long br  = br_base + slot;
    long aofs = (long)blockIdx.x * 128 * 768;
    long bofs = br * 768 * 768 + (long)blockIdx.y * 128 * 768;
    gemm_tile3(nh + aofs, nl + aofs, 768, Wh + bofs, Wl + bofs, 768, 24,
               lds, lds + 4096, lds + 8192, lds + 12288, acc);
    EPI_COORDS;
    long out0 = (long)slot * 8192 * 768;
    long row0 = (long)blockIdx.x * 128;
    long col0 = (long)blockIdx.y * 128;
#pragma unroll
    for (int i = 0; i < 4; ++i)
#pragma unroll
      for (int j = 0; j < 4; ++j)
#pragma unroll
        for (int r = 0; r < 4; ++r) {
          long row = row0 + wi + i * 16 + q * 4 + r;
          long col = col0 + wj + j * 16 + lm;
          float v  = acc[i][j][r];
          f16_t h  = (f16_t)v;
          Thi[out0 + row * 768 + col] = h;
          Tlo[out0 + row * 768 + col] = (f16_t)(v - (float)h);
        }
  } else {
    int id   = blockIdx.x + 64 * (blockIdx.y + 6 * (blockIdx.z - g));  // 0..1151
    int vx   = id % 6;
    int rest = id / 6;
    int vy   = rest & 7;
    int vz   = rest >> 3;        // 0..23
    int b    = vz & 7;
    int br   = vz >> 3;
    f32x4 acc[4][4];
    ZERO_ACC(acc);
    const f16_t* A = paramsT + (long)vx * 128 * 2304 + (long)br * 768;
    const f16_t* B = nh + ((long)b * 1024 + (long)vy * 128) * 768;
    gemm_tile(A, 2304, B, 768, 12, lds, lds + 8192, acc);
    EPI_COORDS;
    f16_t* C = Vt + ((long)(br * 8 + b) * 768) * 1024;
    long row0 = (long)vx * 128;
    long col0 = (long)vy * 128;
#pragma unroll
    for (int i = 0; i < 4; ++i)
#pragma unroll
      for (int j = 0; j < 4; ++j)
#pragma unroll
        for (int r = 0; r < 4; ++r) {
          long row = row0 + wi + i * 16 + q * 4 + r;
          long col = col0 + wj + j * 16 + lm;
          C[row * 1024 + col] = (f16_t)acc[i][j][r];
        }
  }
}

// ---- GEMM2 (fused): S = T @ node^T (Thi@nh + Tlo@nh + Thi@nl), masked, fp32
//      grid (8, 8, 8g); XCD-supertile swizzled. (round-8/10 proven, unchanged)
__global__ __launch_bounds__(256, 4) void k_gemm_scores(const f16_t* __restrict__ Thi,
                                                        const f16_t* __restrict__ Tlo,
                                                        const f16_t* __restrict__ nh,
                                                        const f16_t* __restrict__ nl,
                                                        const int* __restrict__ adj0,
                                                        const int* __restrict__ adj1,
                                                        const int* __restrict__ adj2,
                                                        float* __restrict__ S, int br_base)
{
  __shared__ __align__(16) f16_t lAh[128 * 32];
  __shared__ __align__(16) f16_t lAl[128 * 32];
  __shared__ __align__(16) f16_t lBh[128 * 32];
  __shared__ __align__(16) f16_t lBl[128 * 32];
  f32x4 acc[4][4];
  ZERO_ACC(acc);
  const int g    = gridDim.z >> 3;
  int id   = blockIdx.x + (blockIdx.y << 3) + (blockIdx.z << 6);
  int xcd  = id & 7;
  int step = id >> 3;
  int zz   = xcd * g + (step >> 6);
  int s    = step & 63;
  int bx   = s & 7;
  int by   = s >> 3;
  const int b    = zz & 7;
  const int slot = zz >> 3;
  const int br   = br_base + slot;
  const int* adj = (br == 0) ? adj0 : ((br == 1) ? adj1 : adj2);
  long arow = (long)slot * 8192 * 768 + ((long)b * 1024 + (long)bx * 128) * 768;
  long brow = ((long)b * 1024 + (long)by * 128) * 768;
  gemm_tile3(Thi + arow, Tlo + arow, 768, nh + brow, nl + brow, 768, 24,
             lAh, lAl, lBh, lBl, acc);
  EPI_COORDS;
  const int* adjb = adj + (long)b * 1024 * 1024;
  float* Sb = S + ((long)slot * 8 + b) * 1024 * 1024;
  long row0 = (long)bx * 128;
  long col0 = (long)by * 128;
#pragma unroll
  for (int i = 0; i < 4; ++i)
#pragma unroll
    for (int j = 0; j < 4; ++j)
#pragma unroll
      for (int r = 0; r < 4; ++r) {
        long row = row0 + wi + i * 16 + q * 4 + r;
        long col = col0 + wj + j * 16 + lm;
        float v  = acc[i][j][r];
        v = (adjb[row * 1024 + col] == 1) ? v : -1e7f;
        Sb[row * 1024 + col] = v;
      }
}

// ---- row softmax, WAVE-PER-ROW (4 rows/block, no LDS, no barriers):
//      fp32 S row -> f16 att written IN-PLACE (row stride 2048 f16).
//      Row is wave-private: all reads precede writes in wave program order.
__global__ __launch_bounds__(256) void k_softmax(float* __restrict__ S)
{
  const int wave = threadIdx.x >> 6;
  const int lane = threadIdx.x & 63;
  long row = (long)blockIdx.x * 4 + wave;
  float* rowp = S + row * 1024;
  float4 v[4];
#pragma unroll
  for (int i = 0; i < 4; ++i) v[i] = ((const float4*)rowp)[lane + 64 * i];
  float m = -3e38f;
#pragma unroll
  for (int i = 0; i < 4; ++i)
    m = fmaxf(m, fmaxf(fmaxf(v[i].x, v[i].y), fmaxf(v[i].z, v[i].w)));
#pragma unroll
  for (int off = 32; off; off >>= 1) m = fmaxf(m, __shfl_xor(m, off));
  float e[4][4];
  float s = 0.f;
#pragma unroll
  for (int i = 0; i < 4; ++i) {
    e[i][0] = __expf(v[i].x - m);
    e[i][1] = __expf(v[i].y - m);
    e[i][2] = __expf(v[i].z - m);
    e[i][3] = __expf(v[i].w - m);
    s += e[i][0] + e[i][1] + e[i][2] + e[i][3];
  }
#pragma unroll
  for (int off = 32; off; off >>= 1) s += __shfl_xor(s, off);
  float inv = 1.0f / s;
  f16_t* orow = (f16_t*)rowp;
#pragma unroll
  for (int i = 0; i < 4; ++i) {
    f16x4 o = {(f16_t)(e[i][0] * inv), (f16_t)(e[i][1] * inv),
               (f16_t)(e[i][2] * inv), (f16_t)(e[i][3] * inv)};
    *(f16x4*)(orow + (lane + 64 * i) * 4) = o;
  }
}

// ---- GEMM-PVF (fused pv+final, 128x64 tiles for occupancy):
//      out (+)= sum_slot att_slot @ V[br_base+slot]; grid (8, 12, 8)
__global__ __launch_bounds__(256, 4) void k_gemm_pvf(const float* __restrict__ S,
                                                     const f16_t* __restrict__ Vt,
                                                     float* __restrict__ out,
                                                     int g, int br_base)
{
  __shared__ __align__(16) f16_t lA[128 * 64];  // 16 KB
  __shared__ __align__(16) f16_t lB[64 * 64];   // 8 KB
  f32x4 acc[4][2];
#pragma unroll
  for (int i = 0; i < 4; ++i)
#pragma unroll
    for (int j = 0; j < 2; ++j)
      acc[i][j] = (f32x4){0.f, 0.f, 0.f, 0.f};
  const int b = blockIdx.z;
  for (int s = 0; s < g; ++s) {
    const f16_t* att = (const f16_t*)(S + (long)s * 8 * 1024 * 1024);
    const f16_t* A = att + ((long)b * 1024 + (long)blockIdx.x * 128) * 2048;
    const f16_t* B = Vt + (((long)(br_base + s) * 8 + b) * 768 + (long)blockIdx.y * 64) * 1024;
    gemm_tile_n64(A, 2048, B, 1024, 16, lA, lB, acc);
  }
  const int tid  = threadIdx.x;
  const int wave = tid >> 6;
  const int lane = tid & 63;
  const int lm   = lane & 15;
  const int q    = lane >> 4;
  const int wi   = (wave >> 1) * 64;
  const int wj   = (wave & 1) * 32;
  float* Cb = out + (long)b * 1024 * 768;
  long row0 = (long)blockIdx.x * 128;
  long col0 = (long)blockIdx.y * 64;
#pragma unroll
  for (int i = 0; i < 4; ++i)
#pragma unroll
    for (int j = 0; j < 2; ++j)
#pragma unroll
      for (int r = 0; r < 4; ++r) {
        long row = row0 + wi + i * 16 + q * 4 + r;
        long col = col0 + wj + j * 16 + lm;
        float v  = acc[i][j][r];
        if (br_base != 0) v += Cb[row * 768 + col];
        Cb[row * 768 + col] = v;
      }
}

extern "C" void kernel_launch(void* const* d_in, const int* in_sizes, int n_in,
                              void* d_out, int out_size, void* d_ws, size_t ws_size,
                              hipStream_t stream)
{
  const float* node    = (const float*)d_in[0];
  const int*   adjp[3] = {(const int*)d_in[1], (const int*)d_in[2], (const int*)d_in[3]};
  const float* Wp[3]   = {(const float*)d_in[4], (const float*)d_in[5], (const float*)d_in[6]};
  const float* params  = (const float*)d_in[7];
  float* out = (float*)d_out;

  const size_t SZ_W3 = 3ull * 768 * 768 * 2;     // f16 [3][768][768]
  const size_t SZ_PT = 768ull * 2304 * 2;        // f16 [768][2304]
  const size_t SZ_N  = 8192ull * 768 * 2;        // f16 [8192][768]
  const size_t SZ_VT = 24ull * 768 * 1024 * 2;   // f16 [3][8][768][1024]
  const size_t SZ_T  = 8192ull * 768 * 2;        // f16 per slot (Thi / Tlo)
  const size_t SZ_S  = 8ull * 1024 * 1024 * 4;   // fp32 per slot (S, later att overlay)
  const size_t FIXED = 2 * SZ_W3 + SZ_PT + 2 * SZ_N + SZ_VT;
  const size_t SLOT  = 2 * SZ_T + SZ_S;

  int NBR = 1;
  if (ws_size >= FIXED + 3 * SLOT) NBR = 3;
  else if (ws_size >= FIXED + 2 * SLOT) NBR = 2;
  else if (ws_size < FIXED + SLOT) return;  // can't run

  char* base = (char*)d_ws;
  size_t off = 0;
  f16_t* Wh      = (f16_t*)(base + off); off += SZ_W3;
  f16_t* Wl      = (f16_t*)(base + off); off += SZ_W3;
  f16_t* paramsT = (f16_t*)(base + off); off += SZ_PT;
  f16_t* node_hi = (f16_t*)(base + off); off += SZ_N;
  f16_t* node_lo = (f16_t*)(base + off); off += SZ_N;
  f16_t* Vt      = (f16_t*)(base + off); off += SZ_VT;
  f16_t* Thi     = (f16_t*)(base + off); off += (size_t)NBR * SZ_T;
  f16_t* Tlo     = (f16_t*)(base + off); off += (size_t)NBR * SZ_T;
  float* S       = (float*)(base + off); off += (size_t)NBR * SZ_S;

  k_cvt_split<<<6144, 256, 0, stream>>>(node, node_hi, node_lo);
  k_transpose_all<<<dim3(24, 72, 4), dim3(32, 8), 0, stream>>>(Wp[0], Wp[1], Wp[2], params,
                                                               Wh, Wl, paramsT);

  int done = 0;
  while (done < 3) {
    int g = (3 - done < NBR) ? (3 - done) : NBR;
    int vtz = (done == 0) ? 3 : 0;
    k_tw_vt<<<dim3(64, 6, g + vtz), 256, 0, stream>>>(node_hi, node_lo, Wh, Wl, paramsT,
                                                      Thi, Tlo, Vt, done, g);
    k_gemm_scores<<<dim3(8, 8, 8 * g), 256, 0, stream>>>(Thi, Tlo, node_hi, node_lo,
                                                         adjp[0], adjp[1], adjp[2], S, done);
    k_softmax<<<2048 * g, 256, 0, stream>>>(S);
    k_gemm_pvf<<<dim3(8, 12, 8), 256, 0, stream>>>(S, Vt, out, g, done);
    done += g;
  }
}